// Round 4
// baseline (744.775 us; speedup 1.0000x reference)
//
#include <hip/hip_runtime.h>
#include <math.h>

#define BB 2
#define TT 2048
#define DD 1024
#define NTHREADS 256

#define RT 64               // rows per score tile
#define CT 128              // cols per score tile (= top-K window width)
#define DC 32               // d-chunk
#define NJC (TT / CT)       // 16 windows per row
#define KMAX 16
#define CST 132             // C-tile stride: 4 mod 32 -> 2-way (free) scans
#define NTILES 272          // causal 64x128 tiles per batch: sum_{it<32}(it/2+1)

__device__ __forceinline__ float gelu_exact(float t) {
    return 0.5f * t * (1.0f + erff(t * 0.70710678118654752f));
}

// ---- Kernel S: causal 64x128 score tile (fp32 FMA, 4x8/thread) + per-window top-K ----
__global__ __launch_bounds__(NTHREADS) void score_topk_kernel(
    const float* __restrict__ h,
    float* __restrict__ pval,   // (B,T,NJC,KMAX)
    int*   __restrict__ pidx,   // (B,T,NJC,KMAX)
    int K)
{
    // smem union: staging {Asm[32][64] | Bsm[32][128]} (6144 f) / C tile 64x132 (8448 f)
    __shared__ __align__(16) float smem[RT * CST];
    __shared__ float s_pv[RT][4];
    __shared__ int   s_pc[RT][4];

    // triangular decode: p -> (it, jc); it in [0,32), jc in [0, it/2]
    // group g = it/2 has 2(g+1) tiles; cum(g) = g(g+1)
    const int b = blockIdx.y;
    const int p = blockIdx.x;
    int g = (int)(0.5f * (sqrtf(4.0f * (float)p + 1.0f) - 1.0f));
    while ((g + 1) * (g + 2) <= p) ++g;
    while (g * (g + 1) > p) --g;
    const int qq = p - g * (g + 1);
    const int it = 2 * g + qq / (g + 1);
    const int jc = qq % (g + 1);
    const int i0 = it * RT, j0 = jc * CT;

    const int tid = threadIdx.x;
    const int tx = tid & 15;        // col group: cols {4tx..4tx+3, 64+4tx..64+4tx+3}
    const int ty = tid >> 4;        // row group: rows 4ty..4ty+3
    const float* hb = h + (size_t)b * TT * DD;

    float* Asm = smem;              // [d][64], xor-swizzled
    float* Bsm = smem + RT * DC;    // [d][128], xor-swizzled per 64-col half

    // staging geometry: thread -> (row ra+32s, d-quad da)
    const int ra  = tid >> 3;           // 0..31
    const int da  = (tid & 7) << 2;     // 0..28
    const int swa = tid & 7;            // (d>>2)&7 for this quad
    int posA[2], posB[4];
    #pragma unroll
    for (int s = 0; s < 2; ++s) {
        const int r = ra + 32 * s;      // 0..63
        posA[s] = (r & 3) + 4 * (((r >> 2) ^ swa) & 15);
    }
    #pragma unroll
    for (int s = 0; s < 4; ++s) {
        const int r = ra + 32 * s;      // 0..127
        const int half = r >> 6, rr = r & 63;
        posB[s] = half * 64 + (rr & 3) + 4 * (((rr >> 2) ^ swa) & 15);
    }
    const float* aptr0 = hb + (size_t)(i0 + ra +  0) * DD + da;
    const float* aptr1 = hb + (size_t)(i0 + ra + 32) * DD + da;
    const float* bptr0 = hb + (size_t)(j0 + ra +  0) * DD + da;
    const float* bptr1 = hb + (size_t)(j0 + ra + 32) * DD + da;
    const float* bptr2 = hb + (size_t)(j0 + ra + 64) * DD + da;
    const float* bptr3 = hb + (size_t)(j0 + ra + 96) * DD + da;

    float acc[4][8] = {{0.f}};

    // prefetch chunk 0
    float4 va0 = *(const float4*)(aptr0);
    float4 va1 = *(const float4*)(aptr1);
    float4 vb0 = *(const float4*)(bptr0);
    float4 vb1 = *(const float4*)(bptr1);
    float4 vb2 = *(const float4*)(bptr2);
    float4 vb3 = *(const float4*)(bptr3);

    for (int d0 = 0; d0 < DD; d0 += DC) {
        __syncthreads();
        {
            const float a0[4] = {va0.x, va0.y, va0.z, va0.w};
            const float a1[4] = {va1.x, va1.y, va1.z, va1.w};
            const float b0[4] = {vb0.x, vb0.y, vb0.z, vb0.w};
            const float b1[4] = {vb1.x, vb1.y, vb1.z, vb1.w};
            const float b2[4] = {vb2.x, vb2.y, vb2.z, vb2.w};
            const float b3[4] = {vb3.x, vb3.y, vb3.z, vb3.w};
            #pragma unroll
            for (int t = 0; t < 4; ++t) {
                Asm[(da + t) * RT + posA[0]] = a0[t];
                Asm[(da + t) * RT + posA[1]] = a1[t];
                Bsm[(da + t) * CT + posB[0]] = b0[t];
                Bsm[(da + t) * CT + posB[1]] = b1[t];
                Bsm[(da + t) * CT + posB[2]] = b2[t];
                Bsm[(da + t) * CT + posB[3]] = b3[t];
            }
        }
        __syncthreads();

        if (d0 + DC < DD) {
            const int nd = d0 + DC;
            va0 = *(const float4*)(aptr0 + nd);
            va1 = *(const float4*)(aptr1 + nd);
            vb0 = *(const float4*)(bptr0 + nd);
            vb1 = *(const float4*)(bptr1 + nd);
            vb2 = *(const float4*)(bptr2 + nd);
            vb3 = *(const float4*)(bptr3 + nd);
        }

        #pragma unroll
        for (int d = 0; d < DC; ++d) {
            const int sw = (d >> 2) & 7;
            const float4 af = *(const float4*)&Asm[d * RT + 4 * ((ty ^ sw) & 15)];
            const float4 b0 = *(const float4*)&Bsm[d * CT + 4 * ((tx ^ sw) & 15)];
            const float4 b1 = *(const float4*)&Bsm[d * CT + 64 + 4 * ((tx ^ sw) & 15)];
            const float aa[4] = {af.x, af.y, af.z, af.w};
            const float bb[8] = {b0.x, b0.y, b0.z, b0.w, b1.x, b1.y, b1.z, b1.w};
            #pragma unroll
            for (int r = 0; r < 4; ++r)
                #pragma unroll
                for (int c = 0; c < 8; ++c)
                    acc[r][c] = fmaf(aa[r], bb[c], acc[r][c]);
        }
    }
    __syncthreads();

    // causally-masked C tile into LDS (col-local mapping: c<4 -> 4tx+c, else 64+4tx+c-4)
    #pragma unroll
    for (int r = 0; r < 4; ++r) {
        const int i = i0 + ty * 4 + r;
        #pragma unroll
        for (int c = 0; c < 8; ++c) {
            const int cl = (c < 4) ? (4 * tx + c) : (64 + 4 * tx + (c - 4));
            const int j = j0 + cl;
            smem[(ty * 4 + r) * CST + cl] = (j <= i) ? acc[r][c] : -INFINITY;
        }
    }
    __syncthreads();

    // per-window top-K: 4 threads/row, K argmax passes
    const int rloc = tid >> 2, seg = tid & 3;
    float* Crow = smem + rloc * CST;
    const int irow = i0 + rloc;
    for (int k = 0; k < K; ++k) {
        float best = -INFINITY; int bc = -1;
        #pragma unroll
        for (int cc = 0; cc < 32; ++cc) {
            const int c = seg + (cc << 2);
            const float v = Crow[c];
            if (v > best) { best = v; bc = c; }
        }
        s_pv[rloc][seg] = best; s_pc[rloc][seg] = bc;
        __syncthreads();
        if (seg == 0) {
            float bv = best; int bcc = bc;
            #pragma unroll
            for (int s2 = 1; s2 < 4; ++s2) {
                const float v = s_pv[rloc][s2]; const int c2 = s_pc[rloc][s2];
                if (c2 >= 0 && (v > bv || (v == bv && (bcc < 0 || c2 < bcc)))) { bv = v; bcc = c2; }
            }
            const size_t base = ((size_t)(b * TT + irow) * NJC + jc) * KMAX + k;
            pval[base] = bv;
            pidx[base] = (bcc >= 0) ? (j0 + bcc) : -1;
            if (bcc >= 0) Crow[bcc] = -INFINITY;
        }
        __syncthreads();
    }
}

// ---- Kernel T: merge window top-Ks, gather, epilogue (optional fused final) ----
__global__ __launch_bounds__(NTHREADS) void merge_agg_kernel(
    const float* __restrict__ h_in,
    float* __restrict__ h_out,
    const float* __restrict__ pval,
    const int*   __restrict__ pidx,
    const float* __restrict__ gain,
    const float* __restrict__ bias,
    const float* __restrict__ log_mix_r,
    const float* __restrict__ log_momentum,
    int K,
    const float* __restrict__ xres,       // non-null => fused (h-x)*scale
    const float* __restrict__ log_scale)
{
    __shared__ float s_wv[4];
    __shared__ int   s_wj[4];
    __shared__ int   s_sel[KMAX];

    const int row = blockIdx.x, b = row / TT, i = row % TT;
    const int tid = threadIdx.x, lane = tid & 63, wave = tid >> 6;
    const float* hb = h_in + (size_t)b * TT * DD;

    const int jcn = i / CT + 1;
    const int ncand = jcn * K;          // <= 256
    float mv = -INFINITY; int mj = -1;
    if (tid < ncand) {
        const int w = tid / K, k = tid - w * K;
        const size_t base = ((size_t)(b * TT + i) * NJC + w) * KMAX + k;
        const int j = pidx[base];
        if (j >= 0) { mj = j; mv = pval[base]; }
    }

    const int count = (i + 1 < K) ? (i + 1) : K;
    for (int k = 0; k < count; ++k) {
        float v = mv; int j = mj;
        #pragma unroll
        for (int off = 32; off >= 1; off >>= 1) {
            const float ov = __shfl_down(v, off, 64);
            const int   oj = __shfl_down(j, off, 64);
            if (oj >= 0 && (ov > v || (ov == v && (j < 0 || oj < j)))) { v = ov; j = oj; }
        }
        if (lane == 0) { s_wv[wave] = v; s_wj[wave] = j; }
        __syncthreads();
        if (tid == 0) {
            float bv = s_wv[0]; int bj = s_wj[0];
            #pragma unroll
            for (int w = 1; w < 4; ++w) {
                const float wv = s_wv[w]; const int wj = s_wj[w];
                if (wj >= 0 && (wv > bv || (wv == bv && (bj < 0 || wj < bj)))) { bv = wv; bj = wj; }
            }
            s_sel[k] = bj;
        }
        __syncthreads();
        if (mj >= 0 && mj == s_sel[k]) { mv = -INFINITY; mj = -1; }
    }

    const float mix      = 1.0f / (1.0f + expf(-log_mix_r[0]));
    const float momentum = 1.0f / (1.0f + expf(-log_momentum[0]));
    const float inv_cnt  = 1.0f / (float)count;

    float4 msg = make_float4(0.f, 0.f, 0.f, 0.f);
    for (int k = 0; k < count; ++k) {
        const float4 v = ((const float4*)(hb + (size_t)s_sel[k] * DD))[tid];
        msg.x += v.x; msg.y += v.y; msg.z += v.z; msg.w += v.w;
    }

    const float4 hi = ((const float4*)(hb + (size_t)i * DD))[tid];
    const float4 g4 = ((const float4*)gain)[tid];
    const float4 c4 = ((const float4*)bias)[tid];

    float4 o;
    {
        float m, t;
        m = msg.x * inv_cnt; t = (mix * hi.x + (1.f - mix) * m) * g4.x + c4.x;
        o.x = momentum * hi.x + (1.f - momentum) * gelu_exact(t);
        m = msg.y * inv_cnt; t = (mix * hi.y + (1.f - mix) * m) * g4.y + c4.y;
        o.y = momentum * hi.y + (1.f - momentum) * gelu_exact(t);
        m = msg.z * inv_cnt; t = (mix * hi.z + (1.f - mix) * m) * g4.z + c4.z;
        o.z = momentum * hi.z + (1.f - momentum) * gelu_exact(t);
        m = msg.w * inv_cnt; t = (mix * hi.w + (1.f - mix) * m) * g4.w + c4.w;
        o.w = momentum * hi.w + (1.f - momentum) * gelu_exact(t);
    }

    if (xres != nullptr) {
        const float scale = log1pf(expf(log_scale[0])) + 0.01f;
        const float4 xv = ((const float4*)(xres + (size_t)row * DD))[tid];
        o.x = (o.x - xv.x) * scale;
        o.y = (o.y - xv.y) * scale;
        o.z = (o.z - xv.z) * scale;
        o.w = (o.w - xv.w) * scale;
    }
    ((float4*)(h_out + (size_t)row * DD))[tid] = o;
}

extern "C" void kernel_launch(void* const* d_in, const int* in_sizes, int n_in,
                              void* d_out, int out_size, void* d_ws, size_t ws_size,
                              hipStream_t stream) {
    const float* x            = (const float*)d_in[0];
    const float* gain         = (const float*)d_in[1];
    const float* bias         = (const float*)d_in[2];
    const float* log_mix      = (const float*)d_in[3];
    const float* log_momentum = (const float*)d_in[4];
    const float* log_scale    = (const float*)d_in[5];
    float* out = (float*)d_out;

    // ws: h buffer (16.78 MB) | pval (4.19 MB) | pidx (4.19 MB)
    float* h_ws = (float*)d_ws;
    float* pval = (float*)((char*)d_ws + (size_t)BB * TT * DD * 4);
    int*   pidx = (int*)((char*)pval + (size_t)BB * TT * NJC * KMAX * 4);

    const dim3 sgrid(NTILES, BB);

    // buffer rotation: x -> out -> h_ws -> out(final, fused)
    score_topk_kernel<<<sgrid, NTHREADS, 0, stream>>>(x, pval, pidx, 4);
    merge_agg_kernel<<<BB * TT, NTHREADS, 0, stream>>>(
        x, out, pval, pidx, gain + 0 * DD, bias + 0 * DD, log_mix + 0, log_momentum, 4,
        nullptr, nullptr);
    score_topk_kernel<<<sgrid, NTHREADS, 0, stream>>>(out, pval, pidx, 8);
    merge_agg_kernel<<<BB * TT, NTHREADS, 0, stream>>>(
        out, h_ws, pval, pidx, gain + 1 * DD, bias + 1 * DD, log_mix + 1, log_momentum, 8,
        nullptr, nullptr);
    score_topk_kernel<<<sgrid, NTHREADS, 0, stream>>>(h_ws, pval, pidx, 16);
    merge_agg_kernel<<<BB * TT, NTHREADS, 0, stream>>>(
        h_ws, out, pval, pidx, gain + 2 * DD, bias + 2 * DD, log_mix + 2, log_momentum, 16,
        x, log_scale);
}